// Round 1
// baseline (1357.817 us; speedup 1.0000x reference)
//
#include <hip/hip_runtime.h>
#include <hip/hip_bf16.h>

#define N_NODES 400000
#define N_EDGES 1600000
#define N_GRAPHS 16384

__device__ __forceinline__ float rlane(float x, int k) {
    return __int_as_float(__builtin_amdgcn_readlane(__float_as_int(x), k));
}

__global__ void k_hist_edges(const int* __restrict__ rows, int* __restrict__ degcnt, int E) {
    int e = blockIdx.x * blockDim.x + threadIdx.x;
    if (e < E) atomicAdd(&degcnt[rows[e]], 1);
}

__global__ void k_hist_batch(const int* __restrict__ batch, int* __restrict__ gcnt, int N) {
    int i = blockIdx.x * blockDim.x + threadIdx.x;
    if (i < N) atomicAdd(&gcnt[batch[i]], 1);
}

__global__ void k_dinv(const int* __restrict__ degcnt, float* __restrict__ dinv, int N) {
    int i = blockIdx.x * blockDim.x + threadIdx.x;
    if (i < N) dinv[i] = rsqrtf((float)degcnt[i] + 1.0f);
}

// ---- scan: per-block sums ----
__global__ void k_scan_blocksum(const int* __restrict__ src, int* __restrict__ bsum, int n) {
    __shared__ int s[256];
    int t = threadIdx.x;
    int idx = blockIdx.x * 256 + t;
    int v = idx < n ? src[idx] : 0;
    s[t] = v; __syncthreads();
    for (int off = 128; off > 0; off >>= 1) {
        if (t < off) s[t] += s[t + off];
        __syncthreads();
    }
    if (t == 0) bsum[blockIdx.x] = s[0];
}

// ---- scan: single-block exclusive scan over n elements (looped) ----
__global__ void k_scan_single(const int* __restrict__ src, int* __restrict__ dst, int n) {
    __shared__ int s[256];
    __shared__ int carry_s;
    int t = threadIdx.x;
    if (t == 0) carry_s = 0;
    __syncthreads();
    for (int base = 0; base < n; base += 256) {
        int idx = base + t;
        int v = idx < n ? src[idx] : 0;
        s[t] = v; __syncthreads();
        for (int off = 1; off < 256; off <<= 1) {
            int x = (t >= off) ? s[t - off] : 0;
            __syncthreads();
            s[t] += x;
            __syncthreads();
        }
        int incl = s[t];
        int carry = carry_s;
        if (idx < n) dst[idx] = carry + incl - v;
        __syncthreads();
        if (t == 255) carry_s = carry + incl;
        __syncthreads();
    }
}

// ---- scan: final per-block exclusive scan + block offset ----
__global__ void k_scan_final(const int* __restrict__ src, const int* __restrict__ boffs,
                             int* __restrict__ dst, int n) {
    __shared__ int s[256];
    int t = threadIdx.x;
    int idx = blockIdx.x * 256 + t;
    int v = idx < n ? src[idx] : 0;
    s[t] = v; __syncthreads();
    for (int off = 1; off < 256; off <<= 1) {
        int x = (t >= off) ? s[t - off] : 0;
        __syncthreads();
        s[t] += x;
        __syncthreads();
    }
    if (idx < n) dst[idx] = boffs[blockIdx.x] + s[t] - v;
}

__global__ void k_copy(const int* __restrict__ src, int* __restrict__ dst, int n) {
    int i = blockIdx.x * blockDim.x + threadIdx.x;
    if (i < n) dst[i] = src[i];
}

__global__ void k_scatter(const int* __restrict__ rows, const int* __restrict__ colsIn,
                          const float* __restrict__ dinv, int* __restrict__ cursor,
                          int* __restrict__ colsOut, float* __restrict__ wOut, int E) {
    int e = blockIdx.x * blockDim.x + threadIdx.x;
    if (e < E) {
        int r = rows[e];
        int c = colsIn[e];
        int pos = atomicAdd(&cursor[r], 1);
        colsOut[pos] = c;
        wOut[pos] = dinv[c];
    }
}

// ---- fused GCN layer: out[i] = relu( (A_norm @ in)[i] @ W + b ) ----
// one wave per node; lane = output channel; W column in registers.
template <int IN_D>
__global__ void k_gcn(const float* __restrict__ in, const float* __restrict__ W,
                      const float* __restrict__ bias, const int* __restrict__ degcnt,
                      const int* __restrict__ row_ptr, const int* __restrict__ cols,
                      const float* __restrict__ wcol, const float* __restrict__ dinv,
                      float* __restrict__ out, int N) {
    const int lane = threadIdx.x & 63;
    const int wid = (blockIdx.x * blockDim.x + threadIdx.x) >> 6;
    const int nw = (gridDim.x * blockDim.x) >> 6;
    float w_reg[IN_D];
#pragma unroll
    for (int k = 0; k < IN_D; ++k) w_reg[k] = W[k * 64 + lane];
    const float breg = bias[lane];
    const int lane_c = lane & (IN_D - 1);
    for (int i = wid; i < N; i += nw) {
        const float di = dinv[i];
        const int cnt = degcnt[i];
        const int start = row_ptr[i];
        float acc = di * in[i * IN_D + lane_c];
        for (int base = 0; base < cnt; base += 64) {
            int e = base + lane;
            int mycol = 0;
            float myw = 0.0f;
            if (e < cnt) {
                mycol = cols[start + e];
                myw = wcol[start + e];
            }
            int m = min(64, cnt - base);
            for (int j = 0; j < m; ++j) {
                int cj = __builtin_amdgcn_readlane(mycol, j);
                float wj = rlane(myw, j);
                acc = fmaf(wj, in[cj * IN_D + lane_c], acc);
            }
        }
        acc *= di;
        float h = breg;
#pragma unroll
        for (int k = 0; k < IN_D; ++k) {
            h = fmaf(rlane(acc, k), w_reg[k], h);
        }
        h = fmaxf(h, 0.0f);
        out[i * 64 + lane] = h;
    }
}

// ---- pooling: one wave per graph, lane = channel ----
__global__ void k_pool(const float* __restrict__ h, const int* __restrict__ gstart,
                       const int* __restrict__ gcnt, float* __restrict__ pooled, int G) {
    const int lane = threadIdx.x & 63;
    const int wid = (blockIdx.x * blockDim.x + threadIdx.x) >> 6;
    const int nw = (gridDim.x * blockDim.x) >> 6;
    for (int g = wid; g < G; g += nw) {
        int gs = gstart[g], gc = gcnt[g];
        float sum = 0.0f, mx = -3.402823466e38f;
        for (int n = gs; n < gs + gc; ++n) {
            float v = h[n * 64 + lane];
            sum += v;
            mx = fmaxf(mx, v);
        }
        float mean = sum / fmaxf((float)gc, 1.0f);
        float m = gc > 0 ? mx : 0.0f;
        pooled[g * 128 + lane] = mean;
        pooled[g * 128 + 64 + lane] = m;
    }
}

// ---- predictor: fused meta-encoder + MLP head; one wave per graph ----
__global__ void k_pred(const float* __restrict__ pooled, const float* __restrict__ metadata,
                       const int* __restrict__ species, const float* __restrict__ emb,
                       const float* __restrict__ Wm, const float* __restrict__ bm,
                       const float* __restrict__ Wp1, const float* __restrict__ bp1,
                       const float* __restrict__ Wp2, const float* __restrict__ bp2,
                       float* __restrict__ out, int G) {
    __shared__ float Wp1L[208 * 64];
    __shared__ float WmL[16 * 64];
    __shared__ float bp1L[64], bmL[64], Wp2L[64];
    int t = threadIdx.x;
    for (int idx = t; idx < 208 * 64; idx += blockDim.x) Wp1L[idx] = Wp1[idx];
    for (int idx = t; idx < 16 * 64; idx += blockDim.x) WmL[idx] = Wm[idx];
    if (t < 64) {
        bp1L[t] = bp1[t];
        bmL[t] = bm[t];
        Wp2L[t] = Wp2[t];
    }
    __syncthreads();
    const float bp2v = bp2[0];
    const int lane = t & 63;
    const int wid = (blockIdx.x * blockDim.x + t) >> 6;
    const int nw = (gridDim.x * blockDim.x) >> 6;
    for (int g = wid; g < G; g += nw) {
        float f0 = pooled[g * 128 + lane];        // mean
        float f1 = pooled[g * 128 + 64 + lane];   // max
        float md = lane < 16 ? metadata[g * 16 + lane] : 0.0f;
        float m = bmL[lane];
#pragma unroll
        for (int k = 0; k < 16; ++k) m = fmaf(rlane(md, k), WmL[k * 64 + lane], m);
        float f2 = fmaxf(m, 0.0f);                // meta relu
        int sid = species[g];
        float f3 = lane < 16 ? emb[sid * 16 + lane] : 0.0f;  // species emb
        float tacc = bp1L[lane];
#pragma unroll
        for (int k = 0; k < 64; ++k) tacc = fmaf(rlane(f0, k), Wp1L[k * 64 + lane], tacc);
#pragma unroll
        for (int k = 0; k < 64; ++k) tacc = fmaf(rlane(f1, k), Wp1L[(64 + k) * 64 + lane], tacc);
#pragma unroll
        for (int k = 0; k < 64; ++k) tacc = fmaf(rlane(f2, k), Wp1L[(128 + k) * 64 + lane], tacc);
#pragma unroll
        for (int k = 0; k < 16; ++k) tacc = fmaf(rlane(f3, k), Wp1L[(192 + k) * 64 + lane], tacc);
        tacc = fmaxf(tacc, 0.0f);
        float r = tacc * Wp2L[lane];
        for (int off = 32; off > 0; off >>= 1) r += __shfl_down(r, off);
        if (lane == 0) out[g] = r + bp2v;
    }
}

extern "C" void kernel_launch(void* const* d_in, const int* in_sizes, int n_in,
                              void* d_out, int out_size, void* d_ws, size_t ws_size,
                              hipStream_t stream) {
    const int N = N_NODES, E = N_EDGES, G = N_GRAPHS;

    const float* x        = (const float*)d_in[0];
    const float* metadata = (const float*)d_in[1];
    const int*   ei       = (const int*)d_in[2];
    const int*   batch    = (const int*)d_in[3];
    const int*   species  = (const int*)d_in[4];
    const float* W1 = (const float*)d_in[5];
    const float* b1 = (const float*)d_in[6];
    const float* W2 = (const float*)d_in[7];
    const float* b2 = (const float*)d_in[8];
    const float* W3 = (const float*)d_in[9];
    const float* b3 = (const float*)d_in[10];
    const float* Wm = (const float*)d_in[11];
    const float* bm = (const float*)d_in[12];
    const float* emb = (const float*)d_in[13];
    const float* Wp1 = (const float*)d_in[14];
    const float* bp1 = (const float*)d_in[15];
    const float* Wp2 = (const float*)d_in[16];
    const float* bp2 = (const float*)d_in[17];
    float* out = (float*)d_out;

    char* ws = (char*)d_ws;
    size_t off = 0;
    auto alloc = [&](size_t bytes) -> void* {
        void* p = ws + off;
        off = (off + bytes + 255) & ~(size_t)255;
        return p;
    };
    int*   degcnt  = (int*)alloc((size_t)N * 4);
    int*   gcnt    = (int*)alloc((size_t)G * 4);
    float* dinv    = (float*)alloc((size_t)N * 4);
    int*   row_ptr = (int*)alloc((size_t)N * 4);
    int*   cursor  = (int*)alloc((size_t)N * 4);
    int*   bsum    = (int*)alloc(2048 * 4);
    int*   boffs   = (int*)alloc(2048 * 4);
    int*   gstart  = (int*)alloc((size_t)G * 4);
    int*   colsS   = (int*)alloc((size_t)E * 4);
    float* wcolS   = (float*)alloc((size_t)E * 4);
    float* hA      = (float*)alloc((size_t)N * 64 * 4);
    float* hB      = (float*)alloc((size_t)N * 64 * 4);
    float* pooled  = (float*)alloc((size_t)G * 128 * 4);

    const int nbN = (N + 255) / 256;  // 1563
    const int nbE = (E + 255) / 256;  // 6250

    hipMemsetAsync(degcnt, 0, (size_t)N * 4, stream);
    hipMemsetAsync(gcnt, 0, (size_t)G * 4, stream);

    k_hist_edges<<<nbE, 256, 0, stream>>>(ei, degcnt, E);
    k_hist_batch<<<nbN, 256, 0, stream>>>(batch, gcnt, N);
    k_dinv<<<nbN, 256, 0, stream>>>(degcnt, dinv, N);

    k_scan_blocksum<<<nbN, 256, 0, stream>>>(degcnt, bsum, N);
    k_scan_single<<<1, 256, 0, stream>>>(bsum, boffs, nbN);
    k_scan_final<<<nbN, 256, 0, stream>>>(degcnt, boffs, row_ptr, N);
    k_copy<<<nbN, 256, 0, stream>>>(row_ptr, cursor, N);
    k_scatter<<<nbE, 256, 0, stream>>>(ei, ei + E, dinv, cursor, colsS, wcolS, E);

    k_scan_single<<<1, 256, 0, stream>>>(gcnt, gstart, G);

    k_gcn<32><<<2048, 256, 0, stream>>>(x, W1, b1, degcnt, row_ptr, colsS, wcolS, dinv, hA, N);
    k_gcn<64><<<2048, 256, 0, stream>>>(hA, W2, b2, degcnt, row_ptr, colsS, wcolS, dinv, hB, N);
    k_gcn<64><<<2048, 256, 0, stream>>>(hB, W3, b3, degcnt, row_ptr, colsS, wcolS, dinv, hA, N);

    k_pool<<<1024, 256, 0, stream>>>(hA, gstart, gcnt, pooled, G);

    k_pred<<<512, 256, 0, stream>>>(pooled, metadata, species, emb, Wm, bm, Wp1, bp1, Wp2,
                                    bp2, out, G);
}

// Round 2
// 1152.667 us; speedup vs baseline: 1.1780x; 1.1780x over previous
//
#include <hip/hip_runtime.h>
#include <hip/hip_bf16.h>

#define N_NODES 400000
#define N_EDGES 1600000
#define N_GRAPHS 16384

__device__ __forceinline__ float rlane(float x, int k) {
    return __int_as_float(__builtin_amdgcn_readlane(__float_as_int(x), k));
}

// ---- fused histogram: edge degree + batch counts ----
__global__ void k_hist(const int* __restrict__ rows, const int* __restrict__ batch,
                       int* __restrict__ degcnt, int* __restrict__ gcnt, int E, int N) {
    int t = blockIdx.x * blockDim.x + threadIdx.x;
    if (t < E) atomicAdd(&degcnt[rows[t]], 1);
    if (t < N) atomicAdd(&gcnt[batch[t]], 1);
}

// ---- scan step 1: per-block sums over concat(degcnt, gcnt) ----
__global__ void k_scan_blocksum(const int* __restrict__ src, int* __restrict__ bsum, int n) {
    __shared__ int s[256];
    int t = threadIdx.x;
    int idx = blockIdx.x * 256 + t;
    int v = idx < n ? src[idx] : 0;
    s[t] = v; __syncthreads();
    for (int off = 128; off > 0; off >>= 1) {
        if (t < off) s[t] += s[t + off];
        __syncthreads();
    }
    if (t == 0) bsum[blockIdx.x] = s[0];
}

// ---- scan step 2: single-block exclusive scan of block sums ----
__global__ void k_scan_single(const int* __restrict__ src, int* __restrict__ dst, int n) {
    __shared__ int s[256];
    __shared__ int carry_s;
    int t = threadIdx.x;
    if (t == 0) carry_s = 0;
    __syncthreads();
    for (int base = 0; base < n; base += 256) {
        int idx = base + t;
        int v = idx < n ? src[idx] : 0;
        s[t] = v; __syncthreads();
        for (int off = 1; off < 256; off <<= 1) {
            int x = (t >= off) ? s[t - off] : 0;
            __syncthreads();
            s[t] += x;
            __syncthreads();
        }
        int incl = s[t];
        int carry = carry_s;
        if (idx < n) dst[idx] = carry + incl - v;
        __syncthreads();
        if (t == 255) carry_s = carry + incl;
        __syncthreads();
    }
}

// ---- scan step 3: final exclusive scan + write row_ptr/cursor/dinv/gstart ----
__global__ void k_scan_final(const int* __restrict__ src, const int* __restrict__ boffs,
                             int* __restrict__ row_ptr, int* __restrict__ cursor,
                             float* __restrict__ dinv, int* __restrict__ gstart,
                             int n, int N, int E) {
    __shared__ int s[256];
    int t = threadIdx.x;
    int idx = blockIdx.x * 256 + t;
    int v = idx < n ? src[idx] : 0;
    s[t] = v; __syncthreads();
    for (int off = 1; off < 256; off <<= 1) {
        int x = (t >= off) ? s[t - off] : 0;
        __syncthreads();
        s[t] += x;
        __syncthreads();
    }
    if (idx < n) {
        int excl = boffs[blockIdx.x] + s[t] - v;
        if (idx < N) {
            row_ptr[idx] = excl;
            cursor[idx] = excl;
            dinv[idx] = rsqrtf((float)v + 1.0f);
        } else {
            gstart[idx - N] = excl - E;
        }
    }
}

// ---- scatter edges into CSR, packing (col, dinv[col]) as int2 ----
__global__ void k_scatter(const int* __restrict__ rows, const int* __restrict__ cols,
                          const float* __restrict__ dinv, int* __restrict__ cursor,
                          int2* __restrict__ colw, int E) {
    int e = blockIdx.x * blockDim.x + threadIdx.x;
    if (e < E) {
        int r = rows[e];
        int c = cols[e];
        int pos = atomicAdd(&cursor[r], 1);
        colw[pos] = make_int2(c, __float_as_int(dinv[c]));
    }
}

// ---- fused GCN layer: out[i] = relu( (A_norm @ in)[i] @ W + b ) ----
// Wave split into NSG subgroups of SG lanes; each subgroup gathers one
// neighbor row as float4; 2 gathers per lane per iteration -> 2*NSG edges
// in flight per waitcnt. W column pinned in VGPRs via asm.
template <int IN_D>
__global__ __launch_bounds__(256, 4) void k_gcn(
        const float* __restrict__ in, const float* __restrict__ W,
        const float* __restrict__ bias, const int* __restrict__ cnt_arr,
        const int* __restrict__ row_ptr, const int2* __restrict__ colw,
        const float* __restrict__ dinv, float* __restrict__ out, int N) {
    constexpr int SG = IN_D / 4;   // lanes per subgroup (8 or 16)
    constexpr int NSG = 64 / SG;   // subgroups = concurrent edges per load op
    const int lane = threadIdx.x & 63;
    const int c = lane & (SG - 1);
    const int g = lane / SG;
    const int wid = (blockIdx.x * blockDim.x + threadIdx.x) >> 6;
    const int nw = (gridDim.x * blockDim.x) >> 6;
    const int chunk = (N + nw - 1) / nw;
    const int i0 = wid * chunk;
    const int i1 = min(i0 + chunk, N);

    float w_reg[IN_D];
#pragma unroll
    for (int k = 0; k < IN_D; ++k) {
        w_reg[k] = W[k * 64 + lane];
        asm volatile("" : "+v"(w_reg[k]));  // pin in VGPR, forbid remat
    }
    const float breg = bias[lane];
    const float* inc = in + 4 * c;

    for (int i = i0; i < i1; ++i) {
        const int start = row_ptr[i];
        const int cnt = cnt_arr[i];
        const float di = dinv[i];
        const float4 sf = *(const float4*)(inc + (size_t)i * IN_D);
        float4 acc = {0.f, 0.f, 0.f, 0.f};
        for (int base = 0; base < cnt; base += 64) {
            int e = base + lane;
            int2 cw = make_int2(0, 0);
            if (e < cnt) cw = colw[start + e];
            int m = min(64, cnt - base);
            for (int b = 0; b < m; b += 2 * NSG) {
                int e1 = b + g;
                int e2 = b + NSG + g;
                int cj1 = __shfl(cw.x, e1);
                float wj1 = __int_as_float(__shfl(cw.y, e1));
                int cj2 = __shfl(cw.x, e2);
                float wj2 = __int_as_float(__shfl(cw.y, e2));
                float4 v1 = *(const float4*)(inc + (size_t)cj1 * IN_D);
                float4 v2 = *(const float4*)(inc + (size_t)cj2 * IN_D);
                acc.x = fmaf(wj1, v1.x, acc.x);
                acc.y = fmaf(wj1, v1.y, acc.y);
                acc.z = fmaf(wj1, v1.z, acc.z);
                acc.w = fmaf(wj1, v1.w, acc.w);
                acc.x = fmaf(wj2, v2.x, acc.x);
                acc.y = fmaf(wj2, v2.y, acc.y);
                acc.z = fmaf(wj2, v2.z, acc.z);
                acc.w = fmaf(wj2, v2.w, acc.w);
            }
        }
#pragma unroll
        for (int s = SG; s < 64; s <<= 1) {
            acc.x += __shfl_xor(acc.x, s);
            acc.y += __shfl_xor(acc.y, s);
            acc.z += __shfl_xor(acc.z, s);
            acc.w += __shfl_xor(acc.w, s);
        }
        // agg = di * (sum_j dinv[j] h_j + di * h_i); lane holds channels 4c..4c+3
        acc.x = (acc.x + di * sf.x) * di;
        acc.y = (acc.y + di * sf.y) * di;
        acc.z = (acc.z + di * sf.z) * di;
        acc.w = (acc.w + di * sf.w) * di;
        // dense matvec: h[lane] = b[lane] + sum_k agg[k] * W[k][lane]
        float h0 = breg, h1 = 0.f, h2 = 0.f, h3 = 0.f;
#pragma unroll
        for (int k = 0; k < IN_D; k += 4) {
            const int src = k >> 2;  // home lane of agg[k..k+3] (subgroup 0)
            h0 = fmaf(rlane(acc.x, src), w_reg[k + 0], h0);
            h1 = fmaf(rlane(acc.y, src), w_reg[k + 1], h1);
            h2 = fmaf(rlane(acc.z, src), w_reg[k + 2], h2);
            h3 = fmaf(rlane(acc.w, src), w_reg[k + 3], h3);
        }
        float h = fmaxf((h0 + h1) + (h2 + h3), 0.0f);
        out[(size_t)i * 64 + lane] = h;
    }
}

// ---- pooling: wave per graph, 4 nodes in flight (16-lane float4 subgroups) ----
__global__ void k_pool(const float* __restrict__ h, const int* __restrict__ gstart,
                       const int* __restrict__ gcnt, float* __restrict__ pooled, int G) {
    const int lane = threadIdx.x & 63;
    const int c = lane & 15;
    const int g = lane >> 4;
    const int wid = (blockIdx.x * blockDim.x + threadIdx.x) >> 6;
    const int nw = (gridDim.x * blockDim.x) >> 6;
    const float NEG = -3.402823466e38f;
    for (int gr = wid; gr < G; gr += nw) {
        int gs = gstart[gr], gc = gcnt[gr];
        float4 sum = {0.f, 0.f, 0.f, 0.f};
        float4 mx = {NEG, NEG, NEG, NEG};
        const float* base = h + (size_t)gs * 64 + 4 * c;
        for (int p = g; p < gc; p += 4) {
            float4 v = *(const float4*)(base + (size_t)p * 64);
            sum.x += v.x; sum.y += v.y; sum.z += v.z; sum.w += v.w;
            mx.x = fmaxf(mx.x, v.x); mx.y = fmaxf(mx.y, v.y);
            mx.z = fmaxf(mx.z, v.z); mx.w = fmaxf(mx.w, v.w);
        }
#pragma unroll
        for (int s = 16; s < 64; s <<= 1) {
            sum.x += __shfl_xor(sum.x, s); sum.y += __shfl_xor(sum.y, s);
            sum.z += __shfl_xor(sum.z, s); sum.w += __shfl_xor(sum.w, s);
            mx.x = fmaxf(mx.x, __shfl_xor(mx.x, s));
            mx.y = fmaxf(mx.y, __shfl_xor(mx.y, s));
            mx.z = fmaxf(mx.z, __shfl_xor(mx.z, s));
            mx.w = fmaxf(mx.w, __shfl_xor(mx.w, s));
        }
        float inv = 1.0f / fmaxf((float)gc, 1.0f);
        float4 mean = {sum.x * inv, sum.y * inv, sum.z * inv, sum.w * inv};
        float4 mxo = gc > 0 ? mx : make_float4(0.f, 0.f, 0.f, 0.f);
        if (lane < 16) {
            *(float4*)(pooled + (size_t)gr * 128 + 4 * c) = mean;
            *(float4*)(pooled + (size_t)gr * 128 + 64 + 4 * c) = mxo;
        }
    }
}

// ---- predictor: fused meta-encoder + MLP head; one wave per graph ----
__global__ void k_pred(const float* __restrict__ pooled, const float* __restrict__ metadata,
                       const int* __restrict__ species, const float* __restrict__ emb,
                       const float* __restrict__ Wm, const float* __restrict__ bm,
                       const float* __restrict__ Wp1, const float* __restrict__ bp1,
                       const float* __restrict__ Wp2, const float* __restrict__ bp2,
                       float* __restrict__ out, int G) {
    __shared__ float Wp1L[208 * 64];
    __shared__ float WmL[16 * 64];
    __shared__ float bp1L[64], bmL[64], Wp2L[64];
    int t = threadIdx.x;
    for (int idx = t; idx < 208 * 64; idx += blockDim.x) Wp1L[idx] = Wp1[idx];
    for (int idx = t; idx < 16 * 64; idx += blockDim.x) WmL[idx] = Wm[idx];
    if (t < 64) {
        bp1L[t] = bp1[t];
        bmL[t] = bm[t];
        Wp2L[t] = Wp2[t];
    }
    __syncthreads();
    const float bp2v = bp2[0];
    const int lane = t & 63;
    const int wid = (blockIdx.x * blockDim.x + t) >> 6;
    const int nw = (gridDim.x * blockDim.x) >> 6;
    for (int g = wid; g < G; g += nw) {
        float f0 = pooled[g * 128 + lane];        // mean
        float f1 = pooled[g * 128 + 64 + lane];   // max
        float md = lane < 16 ? metadata[g * 16 + lane] : 0.0f;
        float m = bmL[lane];
#pragma unroll
        for (int k = 0; k < 16; ++k) m = fmaf(rlane(md, k), WmL[k * 64 + lane], m);
        float f2 = fmaxf(m, 0.0f);                // meta relu
        int sid = species[g];
        float f3 = lane < 16 ? emb[sid * 16 + lane] : 0.0f;  // species emb
        float tacc = bp1L[lane];
#pragma unroll
        for (int k = 0; k < 64; ++k) tacc = fmaf(rlane(f0, k), Wp1L[k * 64 + lane], tacc);
#pragma unroll
        for (int k = 0; k < 64; ++k) tacc = fmaf(rlane(f1, k), Wp1L[(64 + k) * 64 + lane], tacc);
#pragma unroll
        for (int k = 0; k < 64; ++k) tacc = fmaf(rlane(f2, k), Wp1L[(128 + k) * 64 + lane], tacc);
#pragma unroll
        for (int k = 0; k < 16; ++k) tacc = fmaf(rlane(f3, k), Wp1L[(192 + k) * 64 + lane], tacc);
        tacc = fmaxf(tacc, 0.0f);
        float r = tacc * Wp2L[lane];
        for (int off = 32; off > 0; off >>= 1) r += __shfl_down(r, off);
        if (lane == 0) out[g] = r + bp2v;
    }
}

extern "C" void kernel_launch(void* const* d_in, const int* in_sizes, int n_in,
                              void* d_out, int out_size, void* d_ws, size_t ws_size,
                              hipStream_t stream) {
    const int N = N_NODES, E = N_EDGES, G = N_GRAPHS;
    const int NT = N + G;

    const float* x        = (const float*)d_in[0];
    const float* metadata = (const float*)d_in[1];
    const int*   ei       = (const int*)d_in[2];
    const int*   batch    = (const int*)d_in[3];
    const int*   species  = (const int*)d_in[4];
    const float* W1 = (const float*)d_in[5];
    const float* b1 = (const float*)d_in[6];
    const float* W2 = (const float*)d_in[7];
    const float* b2 = (const float*)d_in[8];
    const float* W3 = (const float*)d_in[9];
    const float* b3 = (const float*)d_in[10];
    const float* Wm = (const float*)d_in[11];
    const float* bm = (const float*)d_in[12];
    const float* emb = (const float*)d_in[13];
    const float* Wp1 = (const float*)d_in[14];
    const float* bp1 = (const float*)d_in[15];
    const float* Wp2 = (const float*)d_in[16];
    const float* bp2 = (const float*)d_in[17];
    float* out = (float*)d_out;

    char* ws = (char*)d_ws;
    size_t off = 0;
    auto alloc = [&](size_t bytes) -> void* {
        void* p = ws + off;
        off = (off + bytes + 255) & ~(size_t)255;
        return p;
    };
    int*   cnt     = (int*)alloc((size_t)NT * 4);   // degcnt[N] ++ gcnt[G], one memset
    int*   row_ptr = (int*)alloc((size_t)N * 4);
    int*   cursor  = (int*)alloc((size_t)N * 4);
    float* dinv    = (float*)alloc((size_t)N * 4);
    int*   gstart  = (int*)alloc((size_t)G * 4);
    int*   bsum    = (int*)alloc(2048 * 4);
    int*   boffs   = (int*)alloc(2048 * 4);
    int2*  colw    = (int2*)alloc((size_t)E * 8);
    float* hA      = (float*)alloc((size_t)N * 64 * 4);
    float* hB      = (float*)alloc((size_t)N * 64 * 4);
    float* pooled  = (float*)alloc((size_t)G * 128 * 4);

    int* degcnt = cnt;
    int* gcnt = cnt + N;

    const int nbE = (E + 255) / 256;    // 6250
    const int nbT = (NT + 255) / 256;   // 1627

    hipMemsetAsync(cnt, 0, (size_t)NT * 4, stream);

    k_hist<<<nbE, 256, 0, stream>>>(ei, batch, degcnt, gcnt, E, N);
    k_scan_blocksum<<<nbT, 256, 0, stream>>>(cnt, bsum, NT);
    k_scan_single<<<1, 256, 0, stream>>>(bsum, boffs, nbT);
    k_scan_final<<<nbT, 256, 0, stream>>>(cnt, boffs, row_ptr, cursor, dinv, gstart,
                                          NT, N, E);
    k_scatter<<<nbE, 256, 0, stream>>>(ei, ei + E, dinv, cursor, colw, E);

    k_gcn<32><<<2048, 256, 0, stream>>>(x, W1, b1, degcnt, row_ptr, colw, dinv, hA, N);
    k_gcn<64><<<2048, 256, 0, stream>>>(hA, W2, b2, degcnt, row_ptr, colw, dinv, hB, N);
    k_gcn<64><<<2048, 256, 0, stream>>>(hB, W3, b3, degcnt, row_ptr, colw, dinv, hA, N);

    k_pool<<<1024, 256, 0, stream>>>(hA, gstart, gcnt, pooled, G);

    k_pred<<<512, 256, 0, stream>>>(pooled, metadata, species, emb, Wm, bm, Wp1, bp1, Wp2,
                                    bp2, out, G);
}